// Round 16
// baseline (207.963 us; speedup 1.0000x reference)
//
#include <hip/hip_runtime.h>
#include <cstddef>
#include <cstdint>

#define NB 256
#define NS 20
#define NL 512
#define ND 128
#define NH 768
#define ROWE (NS*(ND+NH))   // 17920 floats per output row

typedef __attribute__((ext_vector_type(4))) float  f32x4;
typedef __attribute__((ext_vector_type(8))) short  bf16x8;
typedef __attribute__((ext_vector_type(4))) unsigned short ushort4v;

#define MFMA16 __builtin_amdgcn_mfma_f32_16x16x32_bf16

__device__ __forceinline__ unsigned short bf16_rne(float v){
    unsigned u = __builtin_bit_cast(unsigned, v);
    u = (u + 0x7fffu + ((u>>16)&1u)) >> 16;
    return (unsigned short)u;
}
__device__ __forceinline__ float bf16f(unsigned short h){
    unsigned u = ((unsigned)h)<<16;
    return __builtin_bit_cast(float, u);
}
// LDS-only barrier (no vmcnt drain).
__device__ __forceinline__ void bar_lds(){
    asm volatile("s_waitcnt lgkmcnt(0)" ::: "memory");
    __builtin_amdgcn_s_barrier();
}

// ---------------------------------------------------------------------------
// K1: se = embs[skills[b]] -> out (concat left part);  q = se @ W -> bf16
// hi/lo arrays in ws. 256 blocks x 256 threads; wave w owns s in [5w,5w+5).
// ---------------------------------------------------------------------------
extern "C" __global__ __launch_bounds__(256)
void k1_q(const int* __restrict__ skills, const float* __restrict__ embs,
          const float* __restrict__ W,
          unsigned short* __restrict__ qhi, unsigned short* __restrict__ qlo,
          float* __restrict__ out)
{
    __shared__ float se[NS*ND];
    __shared__ int   sk[NS];
    const int b = blockIdx.x, t = threadIdx.x;
    if (t < NS) sk[t] = skills[b*NS + t];
    __syncthreads();
    for (int idx = t; idx < NS*ND; idx += 256) {
        const int s = idx >> 7, d = idx & (ND-1);
        const float v = embs[(size_t)sk[s]*ND + d];
        se[idx] = v;
        out[(size_t)b*ROWE + (size_t)s*(ND+NH) + d] = v;
    }
    __syncthreads();

    const int w = t >> 6, lane = t & 63;
    float acc[5][12];
    #pragma unroll
    for (int i = 0; i < 5; ++i)
        #pragma unroll
        for (int c = 0; c < 12; ++c) acc[i][c] = 0.f;

    const float* Wl = W + lane;
    for (int d4 = 0; d4 < ND/4; ++d4) {
        f32x4 sv[5];
        #pragma unroll
        for (int i = 0; i < 5; ++i)
            sv[i] = *(const f32x4*)&se[(5*w + i)*ND + 4*d4];
        #pragma unroll
        for (int r = 0; r < 4; ++r) {
            const float* wr = Wl + (size_t)(4*d4 + r)*NH;
            float wv[12];
            #pragma unroll
            for (int c = 0; c < 12; ++c) wv[c] = wr[64*c];
            #pragma unroll
            for (int i = 0; i < 5; ++i) {
                const float s_ = sv[i][r];
                #pragma unroll
                for (int c = 0; c < 12; ++c) acc[i][c] += s_*wv[c];
            }
        }
    }
    #pragma unroll
    for (int i = 0; i < 5; ++i)
        #pragma unroll
        for (int c = 0; c < 12; ++c) {
            const size_t idx = ((size_t)b*NS + 5*w + i)*NH + lane + 64*c;
            const float v = acc[i][c];
            const unsigned short hh = bf16_rne(v);
            qhi[idx] = hh;
            qlo[idx] = bf16_rne(v - bf16f(hh));
        }
}

// ---------------------------------------------------------------------------
// K2F: fused flash partial over an l-range of 256.  Grid (NB,2) split by l.
// 512 threads (8 waves); wave w: st = w&1 (QK s-tile), kq = w>>1 (k-quarter).
//
// R16: desc tile lives in LDS as RAW F32, staged by async DMA
// (global_load_lds, width 16) — no staging VALU, no sreg registers.  QK
// builds bf16 hi/lo A-fragments in-register from the f32 it reads (same
// LDS bytes as before: f32 IS hi+lo).  PV is exact f32 (no conversions).
// Row pitch 772 f32 (mod 32 = 4): QK row-column reads 2-way (free), PV
// slot reads conflict-free.  DMA dest is linear; per-lane source row/col
// via magic div-193 (row pitch = 193 16B-chunks incl. 1 pad chunk).
//
// Per tile: QK | B | softmax(kq0) | B | PV | B | DMA(t+1)+vmcnt(0)+B.
// The DMA wait is the only exposed latency; co-resident block (LDS 58KB ->
// 2 blocks/CU, VGPR ~110) computes through it.
// Outputs UNNORMALIZED Opart + (m,sum); k3_fin merges the lh halves.
// ---------------------------------------------------------------------------
#define DTFP  772                 // f32 row pitch
#define CPR   193                 // 16B-chunks per row (772*4/16)

extern "C" __global__ __launch_bounds__(512)
void k2f(const unsigned short* __restrict__ qhi,
         const unsigned short* __restrict__ qlo,
         const float* __restrict__ desc,
         float* __restrict__ Opart, float* __restrict__ ms)
{
    __shared__ __align__(16) float dtf[12544];        // 50176 B (49 KB chunks)
    __shared__ __align__(16) f32x4 scr[3][2][64];     // 6144 B
    __shared__ __align__(16) float p_lds2[16][24];    // 1536 B
    __shared__ float f_lds[2][16];                    // 128 B

    const int b = blockIdx.x, lh = blockIdx.y, t = threadIdx.x;
    const int w = t >> 6, L = t & 63;
    const int st = w & 1, kq = w >> 1;
    const int g = L >> 4, r16 = L & 15;
    const int slot = t % 96, sq = t / 96;    // PV mapping (sq==5 idle in PV)

    const float* dsrc = desc + ((size_t)b*NL + (size_t)lh*256)*NH;
    const int s_in = 16*st + r16;
    const size_t qrow = ((size_t)b*NS + (s_in < NS ? s_in : NS-1))*(size_t)NH;

    // ---- hoist q (hi/lo) for this wave's k-quarter into registers ----
    bf16x8 qhreg[6], qlreg[6];
    #pragma unroll
    for (int kb = 0; kb < 6; ++kb) {
        const int k0 = 192*kq + 32*kb + 8*g;
        qhreg[kb] = *(const bf16x8*)&qhi[qrow + k0];
        qlreg[kb] = *(const bf16x8*)&qlo[qrow + k0];
    }

    f32x4 acc4[4][2];
    #pragma unroll
    for (int j = 0; j < 4; ++j) {
        acc4[j][0] = (f32x4){0.f,0.f,0.f,0.f};
        acc4[j][1] = (f32x4){0.f,0.f,0.f,0.f};
    }
    float m_run = -1e30f, sum_run = 0.f;

    // ---- DMA: stage a 16x768 f32 tile into padded-pitch LDS ----
    // 16B-slot s -> row = s/193, col = s%193 (col 192 = pad).  49 chunk
    // instrs of 1 KB; wave w issues ch = 8i+w (i<6), wave 0 also ch=48.
    auto issue_dma = [&](const float* tsrc){
        #pragma unroll
        for (int i = 0; i < 6; ++i) {
            const int ch = 8*i + w;
            const unsigned s = (unsigned)(ch*64 + L);
            unsigned row = (s*5434u) >> 20;
            unsigned col = s - row*CPR;
            if (row > 15u) row = 15u;
            if (col > 191u) col = 191u;
            const float* gsrc = tsrc + (size_t)row*NH + 4u*col;
            __builtin_amdgcn_global_load_lds(gsrc, &dtf[ch*256], 16, 0, 0);
        }
        if (w == 0) {
            const unsigned s = (unsigned)(48*64 + L);
            unsigned row = (s*5434u) >> 20;
            unsigned col = s - row*CPR;
            if (row > 15u) row = 15u;
            if (col > 191u) col = 191u;
            const float* gsrc = tsrc + (size_t)row*NH + 4u*col;
            __builtin_amdgcn_global_load_lds(gsrc, &dtf[48*256], 16, 0, 0);
        }
    };

    // prologue: tile 0
    issue_dma(dsrc);
    asm volatile("s_waitcnt vmcnt(0)" ::: "memory");
    bar_lds();

    #pragma unroll 1
    for (int tt = 0; tt < 16; ++tt) {
        // ---- QK^T partial: k in [192kq,192kq+192); Ah/Al built from f32 ----
        f32x4 Se = (f32x4){0.f,0.f,0.f,0.f};
        #pragma unroll
        for (int kb = 0; kb < 6; ++kb) {
            const int k0 = 192*kq + 32*kb;
            const f32x4 A0 = *(const f32x4*)&dtf[r16*DTFP + k0 + 8*g];
            const f32x4 A1 = *(const f32x4*)&dtf[r16*DTFP + k0 + 8*g + 4];
            ushort4v h0, h1, l0, l1;
            #pragma unroll
            for (int e = 0; e < 4; ++e) {
                const float x0 = A0[e], x1 = A1[e];
                const unsigned short hh0 = bf16_rne(x0);
                const unsigned short hh1 = bf16_rne(x1);
                h0[e] = hh0;  h1[e] = hh1;
                l0[e] = (unsigned short)(__builtin_bit_cast(unsigned, x0 - bf16f(hh0)) >> 16);
                l1[e] = (unsigned short)(__builtin_bit_cast(unsigned, x1 - bf16f(hh1)) >> 16);
            }
            const bf16x8 Ah = __builtin_bit_cast(bf16x8,
                __builtin_shufflevector(h0, h1, 0,1,2,3,4,5,6,7));
            const bf16x8 Al = __builtin_bit_cast(bf16x8,
                __builtin_shufflevector(l0, l1, 0,1,2,3,4,5,6,7));
            Se = MFMA16(Ah, qhreg[kb], Se, 0,0,0);
            Se = MFMA16(Al, qhreg[kb], Se, 0,0,0);
            Se = MFMA16(Ah, qlreg[kb], Se, 0,0,0);
        }
        if (kq > 0) scr[kq-1][st][L] = Se;
        bar_lds();   // B2: partials ready

        // ---- kq==0 waves: reduce + online softmax ----
        if (kq == 0) {
            Se += scr[0][st][L];
            Se += scr[1][st][L];
            Se += scr[2][st][L];
            // lane holds S[l = 4g+r][s = 16st + r16]
            float pm = fmaxf(fmaxf(Se[0],Se[1]), fmaxf(Se[2],Se[3]));
            pm = fmaxf(pm, __shfl_xor(pm, 16));
            pm = fmaxf(pm, __shfl_xor(pm, 32));
            const float mnew = fmaxf(m_run, pm);
            const float fsc  = __expf(m_run - mnew);
            float pe[4];
            #pragma unroll
            for (int r = 0; r < 4; ++r) pe[r] = __expf(Se[r] - mnew);
            float ts = (pe[0]+pe[1]) + (pe[2]+pe[3]);
            ts += __shfl_xor(ts, 16);
            ts += __shfl_xor(ts, 32);
            sum_run = sum_run*fsc + ts;
            m_run = mnew;
            if (s_in < NS) {           // clamp lanes must not write (R14 fix)
                #pragma unroll
                for (int r = 0; r < 4; ++r)
                    p_lds2[4*g + r][s_in] = pe[r];
            }
            if (L < 16) f_lds[st][L] = fsc;
        }
        bar_lds();   // B3: p_lds2/f_lds ready

        // ---- PV (f32 exact): thread (slot, sq<5) owns h-chunks
        //      {slot, 96+slot} (h = 4slot..+3 and 384+4slot..+3), s = 4sq+j --
        if (sq < 5) {
            #pragma unroll
            for (int j = 0; j < 4; ++j) {
                const int s = 4*sq + j;
                const float f = f_lds[s>>4][s&15];
                acc4[j][0] *= f;  acc4[j][1] *= f;
            }
            #pragma unroll
            for (int l = 0; l < 16; ++l) {
                const f32x4 d0 = *(const f32x4*)&dtf[l*DTFP + 4*slot];
                const f32x4 d1 = *(const f32x4*)&dtf[l*DTFP + 384 + 4*slot];
                const f32x4 pv = *(const f32x4*)&p_lds2[l][4*sq];
                acc4[0][0] += pv[0] * d0;  acc4[0][1] += pv[0] * d1;
                acc4[1][0] += pv[1] * d0;  acc4[1][1] += pv[1] * d1;
                acc4[2][0] += pv[2] * d0;  acc4[2][1] += pv[2] * d1;
                acc4[3][0] += pv[3] * d0;  acc4[3][1] += pv[3] * d1;
            }
        }
        bar_lds();   // B4: all reads of dtf done -> safe to overwrite

        // ---- stage next tile via DMA; wait covered by co-resident block ----
        if (tt < 15) {
            issue_dma(dsrc + (size_t)(tt+1)*16*NH);
            asm volatile("s_waitcnt vmcnt(0)" ::: "memory");
            bar_lds();   // B1: all waves' chunks arrived
        }
    }

    // ---- epilogue: write 1/sum, then store per-half-normalized partials ----
    bar_lds();
    if (kq == 0 && L < 16) f_lds[st][L] = 1.0f / sum_run;
    bar_lds();
    if (sq < 5) {
        #pragma unroll
        for (int j = 0; j < 4; ++j) {
            const int s = 4*sq + j;
            const float inv = f_lds[s>>4][s&15];
            float* Ob = Opart + ((size_t)(b*2 + lh)*NS + s)*NH;
            f32x4 o0 = acc4[j][0], o1 = acc4[j][1];
            o0 *= inv;  o1 *= inv;
            *(f32x4*)&Ob[4*slot]       = o0;
            *(f32x4*)&Ob[384 + 4*slot] = o1;
        }
    }
    if (kq == 0 && L < 16) {
        const int s2 = 16*st + L;
        if (s2 < NS) {
            ms[((size_t)(b*2 + lh)*NS + s2)*2 + 0] = m_run;
            ms[((size_t)(b*2 + lh)*NS + s2)*2 + 1] = sum_run;
        }
    }
}

// ---------------------------------------------------------------------------
// K3: merge the two l-half partials per (b,s).  Each half's O is normalized
// by its own sum; recombine with softmax-of-(m,sum) weights:
//   out = c0*O0 + c1*O1,  c_i = e^{m_i-m} s_i / (e^{m0-m}s0 + e^{m1-m}s1)
// ---------------------------------------------------------------------------
extern "C" __global__ __launch_bounds__(256)
void k3_fin(const float* __restrict__ Opart, const float* __restrict__ ms,
            float* __restrict__ out)
{
    __shared__ float c0s[NS], c1s[NS];
    const int b = blockIdx.x, t = threadIdx.x;
    if (t < NS) {
        const float m0 = ms[((size_t)(b*2 + 0)*NS + t)*2 + 0];
        const float s0 = ms[((size_t)(b*2 + 0)*NS + t)*2 + 1];
        const float m1 = ms[((size_t)(b*2 + 1)*NS + t)*2 + 0];
        const float s1 = ms[((size_t)(b*2 + 1)*NS + t)*2 + 1];
        const float m  = fmaxf(m0, m1);
        const float w0 = __expf(m0 - m)*s0, w1 = __expf(m1 - m)*s1;
        const float inv = 1.0f / (w0 + w1);
        c0s[t] = w0*inv;
        c1s[t] = w1*inv;
    }
    __syncthreads();
    const float* O0 = Opart + (size_t)(b*2 + 0)*NS*NH;
    const float* O1 = Opart + (size_t)(b*2 + 1)*NS*NH;
    #pragma unroll 1
    for (int i4 = t; i4 < NS*NH/4; i4 += 256) {
        const int idx = 4*i4;
        const int s = idx / NH, h = idx - s*NH;
        const f32x4 a = *(const f32x4*)&O0[idx];
        const f32x4 c = *(const f32x4*)&O1[idx];
        const float c0 = c0s[s], c1 = c1s[s];
        f32x4 o;
        o[0] = c0*a[0] + c1*c[0]; o[1] = c0*a[1] + c1*c[1];
        o[2] = c0*a[2] + c1*c[2]; o[3] = c0*a[3] + c1*c[3];
        *(f32x4*)&out[(size_t)b*ROWE + (size_t)s*(ND+NH) + ND + h] = o;
    }
}

// ---------------------------------------------------------------------------
extern "C" void kernel_launch(void* const* d_in, const int* in_sizes, int n_in,
                              void* d_out, int out_size, void* d_ws, size_t ws_size,
                              hipStream_t stream)
{
    const int*   skills = (const int*)  d_in[0];
    const float* desc   = (const float*)d_in[1];
    const float* embs   = (const float*)d_in[2];
    const float* W      = (const float*)d_in[3];
    float* out = (float*)d_out;

    unsigned short* qhi = (unsigned short*)d_ws;          // [NB][NS][NH] bf16
    unsigned short* qlo = qhi + (size_t)NB*NS*NH;         // [NB][NS][NH] bf16
    float* Opart = (float*)(qlo + (size_t)NB*NS*NH);      // [NB*2][NS][NH] f32
    float* ms    = Opart + (size_t)NB*2*NS*NH;            // [NB*2][NS][2]  f32

    k1_q  <<<NB,          256, 0, stream>>>(skills, embs, W, qhi, qlo, out);
    k2f   <<<dim3(NB, 2), 512, 0, stream>>>(qhi, qlo, desc, Opart, ms);
    k3_fin<<<NB,          256, 0, stream>>>(Opart, ms, out);
}